// Round 1
// baseline (7071.732 us; speedup 1.0000x reference)
//
#include <hip/hip_runtime.h>
#include <math.h>

// HydraScaleLM forward, fp32 correctness baseline.
// Shapes: B=2, S=512, D=1024, DEPTH=4, N=16, K=4, R=64, MLP=4096, V=32000.
// M = B*S = 1024 token rows everywhere.

#define DEV __device__ __forceinline__

DEV float silu_f(float x){ return x / (1.f + expf(-x)); }
DEV float gelu_f(float x){ return 0.5f * x * (1.f + erff(x * 0.70710678118654752f)); }
DEV float softplus_f(float x){ return (x > 20.f) ? x : log1pf(expf(x)); }

// ---------------- time embedding ----------------
__global__ __launch_bounds__(256) void k_temb0(const int* __restrict__ ts, float* __restrict__ temb0){
  int t = blockIdx.x*256 + threadIdx.x;            // 1024 threads: (b, i<512)
  if (t >= 2*512) return;
  int b = t >> 9, i = t & 511;
  float tv = (float)ts[b];
  float inv = expf(-(9.210340371976184f/512.f) * (float)i);
  float a = tv * inv;
  temb0[b*1024 + i]       = sinf(a);
  temb0[b*1024 + 512 + i] = cosf(a);
}

__global__ __launch_bounds__(256) void k_temb1(const float* __restrict__ t0, const float* __restrict__ w1,
                                               const float* __restrict__ b1, float* __restrict__ t1){
  int t = blockIdx.x*256 + threadIdx.x;            // 8192 threads: (b, j<4096)
  int b = t >> 12, j = t & 4095;
  const float4* xr = (const float4*)(t0 + b*1024);
  const float4* wr = (const float4*)(w1 + (size_t)j*1024);
  float acc = 0.f;
  for (int k=0;k<256;k++){ float4 x4=xr[k], w4=wr[k];
    acc += x4.x*w4.x + x4.y*w4.y + x4.z*w4.z + x4.w*w4.w; }
  t1[t] = silu_f(acc + b1[j]);
}

__global__ __launch_bounds__(256) void k_temb2(const float* __restrict__ t1, const float* __restrict__ w2,
                                               const float* __restrict__ b2, float* __restrict__ t2){
  int t = blockIdx.x*256 + threadIdx.x;            // 2048 threads: (b, j<1024)
  int b = t >> 10, j = t & 1023;
  const float4* xr = (const float4*)(t1 + b*4096);
  const float4* wr = (const float4*)(w2 + (size_t)j*4096);
  float acc = 0.f;
  for (int k=0;k<1024;k++){ float4 x4=xr[k], w4=wr[k];
    acc += x4.x*w4.x + x4.y*w4.y + x4.z*w4.z + x4.w*w4.w; }
  t2[t] = acc + b2[j];
}

// ---------------- embed ----------------
__global__ __launch_bounds__(256) void k_embed(const int* __restrict__ ids, const float* __restrict__ tok,
                                               const float* __restrict__ t2, float* __restrict__ x){
  int i = blockIdx.x*256 + threadIdx.x;            // 1M
  int bs = i >> 10, d = i & 1023;
  int id = ids[bs];
  x[i] = tok[(size_t)id*1024 + d] + t2[((bs >> 9) << 10) + d];
}

// ---------------- layernorm (row = 1024 elems, block = 256 thr x float4) ----------------
__global__ __launch_bounds__(256) void k_ln(const float* __restrict__ x, const float* __restrict__ sc,
                                            const float* __restrict__ bi, float* __restrict__ o){
  int row = blockIdx.x;
  int t = threadIdx.x;
  float4 v = ((const float4*)(x + (size_t)row*1024))[t];
  float sum = v.x+v.y+v.z+v.w;
  float sq  = v.x*v.x+v.y*v.y+v.z*v.z+v.w*v.w;
  for (int o_=32;o_;o_>>=1){ sum += __shfl_down(sum,o_); sq += __shfl_down(sq,o_); }
  __shared__ float ps[8];
  int lane = t & 63, wid = t >> 6;
  if (lane==0){ ps[wid]=sum; ps[4+wid]=sq; }
  __syncthreads();
  float tot = ps[0]+ps[1]+ps[2]+ps[3];
  float tsq = ps[4]+ps[5]+ps[6]+ps[7];
  float m = tot * (1.f/1024.f);
  float var = tsq*(1.f/1024.f) - m*m;
  float r = rsqrtf(var + 1e-5f);
  float4 s4 = ((const float4*)sc)[t];
  float4 b4 = ((const float4*)bi)[t];
  float4 o4;
  o4.x = (v.x-m)*r*s4.x + b4.x;
  o4.y = (v.y-m)*r*s4.y + b4.y;
  o4.z = (v.z-m)*r*s4.z + b4.z;
  o4.w = (v.w-m)*r*s4.w + b4.w;
  ((float4*)(o + (size_t)row*1024))[t] = o4;
}

// ---------------- causal depthwise conv (K=4) + silu ----------------
__global__ __launch_bounds__(256) void k_conv(const float* __restrict__ xn, const float* __restrict__ cw,
                                              float* __restrict__ u){
  int i = blockIdx.x*256 + threadIdx.x;            // 1M, layout (b,s,d)
  int bs = i >> 10, d = i & 1023;
  int s = bs & 511;
  const float* w = cw + d*4;
  float acc = 0.f;
  #pragma unroll
  for (int j=0;j<4;j++){
    int sj = s - 3 + j;
    if (sj >= 0) acc += xn[i + (j-3)*1024] * w[j];
  }
  u[i] = silu_f(acc);
}

// ---------------- SSM scan: thread per (b,d,n), shfl-reduce over n ----------------
__global__ __launch_bounds__(256) void k_scan(const float* __restrict__ dt, const float* __restrict__ u,
                                              const float* __restrict__ p, const float* __restrict__ alog,
                                              float* __restrict__ y){
  int t = blockIdx.x*256 + threadIdx.x;            // 32768 = B*D*N
  int n = t & 15;
  int d = (t >> 4) & 1023;
  int b = t >> 14;
  float al = alog[d*16 + n];
  float A = -expf(al);
  float invA = 1.f / (A + 1e-10f);
  bool tiny = fabsf(A) < 1e-8f;
  float h = 0.f;
  const float* dtp = dt + (size_t)b*512*1024 + d;
  const float* up  = u  + (size_t)b*512*1024 + d;
  const float* pp  = p  + (size_t)b*512*96;
  float* yp        = y  + (size_t)b*512*1024 + d;
  for (int s=0;s<512;s++){
    float dtv = dtp[s*1024];
    float uv  = up[s*1024];
    float Bpv = pp[s*96 + 64 + n];
    float Cpv = pp[s*96 + 80 + n];
    float At  = expf(dtv * A);
    float Bt  = tiny ? dtv : (At - 1.f) * invA;
    h = At * h + Bt * Bpv * uv;
    float c = Cpv * h;
    c += __shfl_xor(c, 1);
    c += __shfl_xor(c, 2);
    c += __shfl_xor(c, 4);
    c += __shfl_xor(c, 8);
    if (n == 0) yp[s*1024] = c;
  }
}

// ---------------- y = (y + u*Dp) * silu(z) ----------------
__global__ __launch_bounds__(256) void k_ypost(const float* __restrict__ y, const float* __restrict__ u,
                                               const float* __restrict__ z, const float* __restrict__ Dp,
                                               float* __restrict__ y2){
  int i = blockIdx.x*256 + threadIdx.x;            // 1M
  int d = i & 1023;
  float zv = z[i];
  y2[i] = (y[i] + u[i]*Dp[d]) * (zv / (1.f + expf(-zv)));
}

// ---------------- fp32 GEMM: C[m,n] = epi(sum_k A[m,k]*W[n,k]) ----------------
// EPI: 0=none, 1=+bias, 2=+bias,gelu, 3=+bias,softplus, 4=+resid, 5=+bias,+resid
template<int EPI>
__global__ __launch_bounds__(256) void k_gemm(
    const float* __restrict__ A, int lda,
    const float* __restrict__ W,
    const float* __restrict__ bias,
    const float* __restrict__ resid,
    float* __restrict__ C,
    int N, int K)
{
  __shared__ float As[8][128];   // [k][m]
  __shared__ float Bs[8][128];   // [k][n]
  const int t = threadIdx.x;
  const int m0 = blockIdx.y * 128;
  const int n0 = blockIdx.x * 128;
  const int tx = t & 15, ty = t >> 4;
  const int srow = t >> 1;            // 0..127
  const int skq  = (t & 1) * 4;       // 0 or 4
  float acc[8][8];
  #pragma unroll
  for (int i=0;i<8;i++)
    #pragma unroll
    for (int j=0;j<8;j++) acc[i][j]=0.f;

  const float* Aptr = A + (size_t)(m0 + srow)*lda + skq;
  const int gn = n0 + srow;
  const bool bvalid = (gn < N);
  const float* Wptr = W + (size_t)(bvalid ? gn : 0)*K + skq;

  for (int k0 = 0; k0 < K; k0 += 8){
    float4 av = *(const float4*)(Aptr + k0);
    float4 bv = bvalid ? *(const float4*)(Wptr + k0) : make_float4(0.f,0.f,0.f,0.f);
    __syncthreads();
    As[skq+0][srow]=av.x; As[skq+1][srow]=av.y; As[skq+2][srow]=av.z; As[skq+3][srow]=av.w;
    Bs[skq+0][srow]=bv.x; Bs[skq+1][srow]=bv.y; Bs[skq+2][srow]=bv.z; Bs[skq+3][srow]=bv.w;
    __syncthreads();
    #pragma unroll
    for (int k=0;k<8;k++){
      float4 a0 = *(const float4*)&As[k][ty*8];
      float4 a1 = *(const float4*)&As[k][ty*8+4];
      float4 b0 = *(const float4*)&Bs[k][tx*8];
      float4 b1 = *(const float4*)&Bs[k][tx*8+4];
      float ar[8]={a0.x,a0.y,a0.z,a0.w,a1.x,a1.y,a1.z,a1.w};
      float br[8]={b0.x,b0.y,b0.z,b0.w,b1.x,b1.y,b1.z,b1.w};
      #pragma unroll
      for (int i=0;i<8;i++)
        #pragma unroll
        for (int j=0;j<8;j++)
          acc[i][j] = fmaf(ar[i], br[j], acc[i][j]);
    }
  }
  #pragma unroll
  for (int i=0;i<8;i++){
    int m = m0 + ty*8 + i;
    #pragma unroll
    for (int j=0;j<8;j++){
      int n = n0 + tx*8 + j;
      if (n < N){
        float v = acc[i][j];
        if constexpr (EPI==1 || EPI==2 || EPI==3 || EPI==5) v += bias[n];
        if constexpr (EPI==2) v = gelu_f(v);
        if constexpr (EPI==3) v = softplus_f(v);
        if constexpr (EPI==4 || EPI==5) v += resid[(size_t)m*N + n];
        C[(size_t)m*N + n] = v;
      }
    }
  }
}

extern "C" void kernel_launch(void* const* d_in, const int* in_sizes, int n_in,
                              void* d_out, int out_size, void* d_ws, size_t ws_size,
                              hipStream_t stream)
{
  const int*   ids    = (const int*)d_in[0];
  const int*   tsteps = (const int*)d_in[1];
  const float* tok    = (const float*)d_in[2];
  const float* tw1    = (const float*)d_in[3];
  const float* tb1    = (const float*)d_in[4];
  const float* tw2    = (const float*)d_in[5];
  const float* tb2    = (const float*)d_in[6];
  const float* n1s    = (const float*)d_in[7];
  const float* n1b    = (const float*)d_in[8];
  // d_in[9] = xW, unused by the reference
  const float* zW     = (const float*)d_in[10];
  const float* pW     = (const float*)d_in[11];
  const float* cW     = (const float*)d_in[12];
  const float* dtW    = (const float*)d_in[13];
  const float* dtb    = (const float*)d_in[14];
  const float* alog   = (const float*)d_in[15];
  const float* Dp     = (const float*)d_in[16];
  const float* oW     = (const float*)d_in[17];
  const float* n2s    = (const float*)d_in[18];
  const float* n2b    = (const float*)d_in[19];
  const float* m1W    = (const float*)d_in[20];
  const float* m1b    = (const float*)d_in[21];
  const float* m2W    = (const float*)d_in[22];
  const float* m2b    = (const float*)d_in[23];
  const float* nos    = (const float*)d_in[24];
  const float* nob    = (const float*)d_in[25];
  const float* hW     = (const float*)d_in[26];
  const float* hb     = (const float*)d_in[27];

  float* ws = (float*)d_ws;
  const size_t MEG = 1u<<20;
  float* x   = ws;            // 1M floats (1024x1024)
  float* xn  = ws + 1*MEG;
  float* z   = ws + 2*MEG;
  float* dt  = ws + 3*MEG;
  float* u   = ws + 4*MEG;
  float* y   = ws + 5*MEG;
  float* y2  = ws + 6*MEG;
  float* h1  = ws + 7*MEG;    // 4M floats (1024x4096)
  float* p   = ws + 11*MEG;   // 1024x96
  float* t0  = p + 1024*96;
  float* t1  = t0 + 2048;
  float* t2  = t1 + 8192;

  dim3 blk(256);
  k_temb0<<<dim3(4),  blk, 0, stream>>>(tsteps, t0);
  k_temb1<<<dim3(32), blk, 0, stream>>>(t0, tw1, tb1, t1);
  k_temb2<<<dim3(8),  blk, 0, stream>>>(t1, tw2, tb2, t2);
  k_embed<<<dim3(4096), blk, 0, stream>>>(ids, tok, t2, x);

  for (int l=0; l<4; l++){
    k_ln<<<dim3(1024), blk, 0, stream>>>(x, n1s + l*1024, n1b + l*1024, xn);
    k_gemm<0><<<dim3(8,8),  blk, 0, stream>>>(xn, 1024, zW + (size_t)l*1024*1024, nullptr, nullptr, z, 1024, 1024);
    k_gemm<0><<<dim3(1,8),  blk, 0, stream>>>(xn, 1024, pW + (size_t)l*96*1024,   nullptr, nullptr, p, 96, 1024);
    k_gemm<3><<<dim3(8,8),  blk, 0, stream>>>(p, 96, dtW + (size_t)l*1024*64, dtb + l*1024, nullptr, dt, 1024, 64);
    k_conv<<<dim3(4096), blk, 0, stream>>>(xn, cW + l*1024*4, u);
    k_scan<<<dim3(128), blk, 0, stream>>>(dt, u, p, alog + l*1024*16, y);
    k_ypost<<<dim3(4096), blk, 0, stream>>>(y, u, z, Dp + l*1024, y2);
    k_gemm<4><<<dim3(8,8),  blk, 0, stream>>>(y2, 1024, oW + (size_t)l*1024*1024, nullptr, x, x, 1024, 1024);
    k_ln<<<dim3(1024), blk, 0, stream>>>(x, n2s + l*1024, n2b + l*1024, xn);
    k_gemm<2><<<dim3(32,8), blk, 0, stream>>>(xn, 1024, m1W + (size_t)l*4096*1024, m1b + l*4096, nullptr, h1, 4096, 1024);
    k_gemm<5><<<dim3(8,8),  blk, 0, stream>>>(h1, 4096, m2W + (size_t)l*1024*4096, m2b + l*1024, x, x, 1024, 4096);
  }
  k_ln<<<dim3(1024), blk, 0, stream>>>(x, nos, nob, xn);
  k_gemm<1><<<dim3(250,8), blk, 0, stream>>>(xn, 1024, hW, hb, nullptr, (float*)d_out, 32000, 1024);
}

// Round 2
// 2882.259 us; speedup vs baseline: 2.4535x; 2.4535x over previous
//
#include <hip/hip_runtime.h>
#include <math.h>

// HydraScaleLM forward. Round 2: bf16 MFMA for all big GEMMs (m97 structure:
// 128x128 tile, BK=64, global_load_lds width 16, linear LDS), fp32 elsewhere.
// Shapes: B=2, S=512, D=1024, DEPTH=4, N=16, K=4, R=64, MLP=4096, V=32000. M=1024.

#define DEV __device__ __forceinline__
typedef unsigned int u32;
typedef unsigned short ushort;
typedef __bf16 bf16x8 __attribute__((ext_vector_type(8)));
typedef float f32x4 __attribute__((ext_vector_type(4)));

DEV float silu_f(float x){ return x / (1.f + expf(-x)); }
DEV float gelu_f(float x){ return 0.5f * x * (1.f + erff(x * 0.70710678118654752f)); }
DEV float softplus_f(float x){ return (x > 20.f) ? x : log1pf(expf(x)); }
DEV ushort f2b(float f){
  u32 u = __builtin_bit_cast(u32, f);
  return (ushort)((u + 0x7fffu + ((u >> 16) & 1u)) >> 16);
}

DEV void gl_lds16(const ushort* g, ushort* l){
  __builtin_amdgcn_global_load_lds(
      (const __attribute__((address_space(1))) u32*)g,
      (__attribute__((address_space(3))) u32*)l, 16, 0, 0);
}

// ---------------- fp32 -> bf16 conversion (weights) ----------------
__global__ __launch_bounds__(256) void k_cvt(const float* __restrict__ in, ushort* __restrict__ out, int n4){
  int i = blockIdx.x*256 + threadIdx.x;
  if (i >= n4) return;
  float4 v = ((const float4*)in)[i];
  ushort4 o; o.x=f2b(v.x); o.y=f2b(v.y); o.z=f2b(v.z); o.w=f2b(v.w);
  ((ushort4*)out)[i] = o;
}

// ---------------- time embedding ----------------
__global__ __launch_bounds__(256) void k_temb0(const int* __restrict__ ts, float* __restrict__ temb0){
  int t = blockIdx.x*256 + threadIdx.x;
  if (t >= 2*512) return;
  int b = t >> 9, i = t & 511;
  float tv = (float)ts[b];
  float inv = expf(-(9.210340371976184f/512.f) * (float)i);
  float a = tv * inv;
  temb0[b*1024 + i]       = sinf(a);
  temb0[b*1024 + 512 + i] = cosf(a);
}

__global__ __launch_bounds__(256) void k_temb1(const float* __restrict__ t0, const float* __restrict__ w1,
                                               const float* __restrict__ b1, float* __restrict__ t1){
  int t = blockIdx.x*256 + threadIdx.x;
  int b = t >> 12, j = t & 4095;
  const float4* xr = (const float4*)(t0 + b*1024);
  const float4* wr = (const float4*)(w1 + (size_t)j*1024);
  float acc = 0.f;
  for (int k=0;k<256;k++){ float4 x4=xr[k], w4=wr[k];
    acc += x4.x*w4.x + x4.y*w4.y + x4.z*w4.z + x4.w*w4.w; }
  t1[t] = silu_f(acc + b1[j]);
}

__global__ __launch_bounds__(256) void k_temb2(const float* __restrict__ t1, const float* __restrict__ w2,
                                               const float* __restrict__ b2, float* __restrict__ t2){
  int t = blockIdx.x*256 + threadIdx.x;
  int b = t >> 10, j = t & 1023;
  const float4* xr = (const float4*)(t1 + b*4096);
  const float4* wr = (const float4*)(w2 + (size_t)j*4096);
  float acc = 0.f;
  for (int k=0;k<1024;k++){ float4 x4=xr[k], w4=wr[k];
    acc += x4.x*w4.x + x4.y*w4.y + x4.z*w4.z + x4.w*w4.w; }
  t2[t] = acc + b2[j];
}

// ---------------- embed ----------------
__global__ __launch_bounds__(256) void k_embed(const int* __restrict__ ids, const float* __restrict__ tok,
                                               const float* __restrict__ t2, float* __restrict__ x){
  int i = blockIdx.x*256 + threadIdx.x;
  int bs = i >> 10, d = i & 1023;
  int id = ids[bs];
  x[i] = tok[(size_t)id*1024 + d] + t2[((bs >> 9) << 10) + d];
}

// ---------------- layernorm: writes fp32 + bf16 ----------------
__global__ __launch_bounds__(256) void k_ln(const float* __restrict__ x, const float* __restrict__ sc,
                                            const float* __restrict__ bi, float* __restrict__ o,
                                            ushort* __restrict__ obf){
  int row = blockIdx.x;
  int t = threadIdx.x;
  float4 v = ((const float4*)(x + (size_t)row*1024))[t];
  float sum = v.x+v.y+v.z+v.w;
  float sq  = v.x*v.x+v.y*v.y+v.z*v.z+v.w*v.w;
  for (int o_=32;o_;o_>>=1){ sum += __shfl_down(sum,o_); sq += __shfl_down(sq,o_); }
  __shared__ float ps[8];
  int lane = t & 63, wid = t >> 6;
  if (lane==0){ ps[wid]=sum; ps[4+wid]=sq; }
  __syncthreads();
  float tot = ps[0]+ps[1]+ps[2]+ps[3];
  float tsq = ps[4]+ps[5]+ps[6]+ps[7];
  float m = tot * (1.f/1024.f);
  float var = tsq*(1.f/1024.f) - m*m;
  float r = rsqrtf(var + 1e-5f);
  float4 s4 = ((const float4*)sc)[t];
  float4 b4 = ((const float4*)bi)[t];
  float4 o4;
  o4.x = (v.x-m)*r*s4.x + b4.x;
  o4.y = (v.y-m)*r*s4.y + b4.y;
  o4.z = (v.z-m)*r*s4.z + b4.z;
  o4.w = (v.w-m)*r*s4.w + b4.w;
  ((float4*)(o + (size_t)row*1024))[t] = o4;
  ushort4 ob; ob.x=f2b(o4.x); ob.y=f2b(o4.y); ob.z=f2b(o4.z); ob.w=f2b(o4.w);
  ((ushort4*)(obf + (size_t)row*1024))[t] = ob;
}

// ---------------- causal depthwise conv (K=4) + silu ----------------
__global__ __launch_bounds__(256) void k_conv(const float* __restrict__ xn, const float* __restrict__ cw,
                                              float* __restrict__ u){
  int i = blockIdx.x*256 + threadIdx.x;
  int bs = i >> 10, d = i & 1023;
  int s = bs & 511;
  const float* w = cw + d*4;
  float acc = 0.f;
  #pragma unroll
  for (int j=0;j<4;j++){
    int sj = s - 3 + j;
    if (sj >= 0) acc += xn[i + (j-3)*1024] * w[j];
  }
  u[i] = silu_f(acc);
}

// ---------------- SSM scan: thread per (b,d,n) ----------------
__global__ __launch_bounds__(256) void k_scan(const float* __restrict__ dt, const float* __restrict__ u,
                                              const float* __restrict__ p, const float* __restrict__ alog,
                                              float* __restrict__ y){
  int t = blockIdx.x*256 + threadIdx.x;
  int n = t & 15;
  int d = (t >> 4) & 1023;
  int b = t >> 14;
  float al = alog[d*16 + n];
  float A = -expf(al);
  float invA = 1.f / (A + 1e-10f);
  bool tiny = fabsf(A) < 1e-8f;
  float h = 0.f;
  const float* dtp = dt + (size_t)b*512*1024 + d;
  const float* up  = u  + (size_t)b*512*1024 + d;
  const float* pp  = p  + (size_t)b*512*96;
  float* yp        = y  + (size_t)b*512*1024 + d;
  for (int s=0;s<512;s++){
    float dtv = dtp[s*1024];
    float uv  = up[s*1024];
    float Bpv = pp[s*96 + 64 + n];
    float Cpv = pp[s*96 + 80 + n];
    float At  = expf(dtv * A);
    float Bt  = tiny ? dtv : (At - 1.f) * invA;
    h = At * h + Bt * Bpv * uv;
    float c = Cpv * h;
    c += __shfl_xor(c, 1);
    c += __shfl_xor(c, 2);
    c += __shfl_xor(c, 4);
    c += __shfl_xor(c, 8);
    if (n == 0) yp[s*1024] = c;
  }
}

// ---------------- y2 = (y + u*Dp) * silu(z), bf16 out ----------------
__global__ __launch_bounds__(256) void k_ypost(const float* __restrict__ y, const float* __restrict__ u,
                                               const float* __restrict__ z, const float* __restrict__ Dp,
                                               ushort* __restrict__ y2b){
  int i = blockIdx.x*256 + threadIdx.x;
  int d = i & 1023;
  float zv = z[i];
  y2b[i] = f2b((y[i] + u[i]*Dp[d]) * (zv / (1.f + expf(-zv))));
}

// ---------------- fp32 GEMM (small: p, dt) ----------------
// EPI: 0=none, 3=+bias,softplus
template<int EPI>
__global__ __launch_bounds__(256) void k_gemm(
    const float* __restrict__ A, int lda,
    const float* __restrict__ W,
    const float* __restrict__ bias,
    float* __restrict__ C,
    int N, int K)
{
  __shared__ float As[8][128];
  __shared__ float Bs[8][128];
  const int t = threadIdx.x;
  const int m0 = blockIdx.y * 128;
  const int n0 = blockIdx.x * 128;
  const int tx = t & 15, ty = t >> 4;
  const int srow = t >> 1;
  const int skq  = (t & 1) * 4;
  float acc[8][8];
  #pragma unroll
  for (int i=0;i<8;i++)
    #pragma unroll
    for (int j=0;j<8;j++) acc[i][j]=0.f;

  const float* Aptr = A + (size_t)(m0 + srow)*lda + skq;
  const int gn = n0 + srow;
  const bool bvalid = (gn < N);
  const float* Wptr = W + (size_t)(bvalid ? gn : 0)*K + skq;

  for (int k0 = 0; k0 < K; k0 += 8){
    float4 av = *(const float4*)(Aptr + k0);
    float4 bv = bvalid ? *(const float4*)(Wptr + k0) : make_float4(0.f,0.f,0.f,0.f);
    __syncthreads();
    As[skq+0][srow]=av.x; As[skq+1][srow]=av.y; As[skq+2][srow]=av.z; As[skq+3][srow]=av.w;
    Bs[skq+0][srow]=bv.x; Bs[skq+1][srow]=bv.y; Bs[skq+2][srow]=bv.z; Bs[skq+3][srow]=bv.w;
    __syncthreads();
    #pragma unroll
    for (int k=0;k<8;k++){
      float4 a0 = *(const float4*)&As[k][ty*8];
      float4 a1 = *(const float4*)&As[k][ty*8+4];
      float4 b0 = *(const float4*)&Bs[k][tx*8];
      float4 b1 = *(const float4*)&Bs[k][tx*8+4];
      float ar[8]={a0.x,a0.y,a0.z,a0.w,a1.x,a1.y,a1.z,a1.w};
      float br[8]={b0.x,b0.y,b0.z,b0.w,b1.x,b1.y,b1.z,b1.w};
      #pragma unroll
      for (int i=0;i<8;i++)
        #pragma unroll
        for (int j=0;j<8;j++)
          acc[i][j] = fmaf(ar[i], br[j], acc[i][j]);
    }
  }
  #pragma unroll
  for (int i=0;i<8;i++){
    int m = m0 + ty*8 + i;
    #pragma unroll
    for (int j=0;j<8;j++){
      int n = n0 + tx*8 + j;
      if (n < N){
        float v = acc[i][j];
        if constexpr (EPI==3) v = softplus_f(v + bias[n]);
        C[(size_t)m*N + n] = v;
      }
    }
  }
}

// ---------------- bf16 MFMA GEMM: C[m,n] = epi(sum_k A[m,k]*W[n,k]) ----------------
// 128x128 tile, BK=64, 4 waves (2x2), 4x4 fragments of 16x16x32 MFMA.
// A: [M][K] bf16 (row stride K), W: [N][K] bf16. M%128==0, gridN*128 cols, K%64==0.
// EPI: 0=none, 1=+bias, 2=+bias,gelu, 4=+resid, 5=+bias,+resid. OBF: bf16 output.
template<int EPI, bool OBF>
__global__ __launch_bounds__(256) void k_bgemm(
    const ushort* __restrict__ A,
    const ushort* __restrict__ W,
    const float* __restrict__ bias,
    const float* __restrict__ resid,
    void* __restrict__ Cout,
    int ldc, int K)
{
  __shared__ ushort As[128*64] __attribute__((aligned(16)));
  __shared__ ushort Bs[128*64] __attribute__((aligned(16)));
  const int t = threadIdx.x;
  const int w = t >> 6;          // wave 0..3
  const int lane = t & 63;
  const int wm = w >> 1, wn = w & 1;
  const int m0 = blockIdx.y * 128;
  const int n0 = blockIdx.x * 128;

  f32x4 acc[4][4];
  #pragma unroll
  for (int i=0;i<4;i++)
    #pragma unroll
    for (int j=0;j<4;j++) acc[i][j] = (f32x4){0.f,0.f,0.f,0.f};

  const int srow = (lane >> 3);        // 0..7 within 8-row chunk
  const int scol = (lane & 7) * 8;     // elem col 0..56

  for (int k0 = 0; k0 < K; k0 += 64){
    __syncthreads();   // previous compute done before overwrite
    #pragma unroll
    for (int i=0;i<4;i++){
      int chunk = i*4 + w;
      int row = chunk*8 + srow;
      gl_lds16(A + (size_t)(m0 + row)*K + k0 + scol, &As[chunk*512]);
      gl_lds16(W + (size_t)(n0 + row)*K + k0 + scol, &Bs[chunk*512]);
    }
    __syncthreads();   // compiler emits vmcnt(0) drain before barrier
    #pragma unroll
    for (int kk=0; kk<2; ++kk){
      bf16x8 a[4], b[4];
      const int cofs = kk*32 + (lane>>4)*8;
      const int fr = lane & 15;
      #pragma unroll
      for (int am=0; am<4; am++)
        a[am] = *(const bf16x8*)&As[(wm*64 + am*16 + fr)*64 + cofs];
      #pragma unroll
      for (int bn=0; bn<4; bn++)
        b[bn] = *(const bf16x8*)&Bs[(wn*64 + bn*16 + fr)*64 + cofs];
      #pragma unroll
      for (int am=0; am<4; am++)
        #pragma unroll
        for (int bn=0; bn<4; bn++)
          acc[am][bn] = __builtin_amdgcn_mfma_f32_16x16x32_bf16(a[am], b[bn], acc[am][bn], 0, 0, 0);
    }
  }

  // epilogue: C/D layout col=lane&15, row=(lane>>4)*4+reg
  #pragma unroll
  for (int am=0; am<4; am++){
    #pragma unroll
    for (int bn=0; bn<4; bn++){
      int r0 = m0 + wm*64 + am*16 + ((lane>>4)<<2);
      int c  = n0 + wn*64 + bn*16 + (lane&15);
      float bv = 0.f;
      if constexpr (EPI==1 || EPI==2 || EPI==5) bv = bias[c];
      #pragma unroll
      for (int r=0; r<4; r++){
        float v = acc[am][bn][r];
        if constexpr (EPI==1 || EPI==2 || EPI==5) v += bv;
        if constexpr (EPI==2) v = gelu_f(v);
        if constexpr (EPI==4 || EPI==5) v += resid[(size_t)(r0+r)*ldc + c];
        if constexpr (OBF)
          ((ushort*)Cout)[(size_t)(r0+r)*ldc + c] = f2b(v);
        else
          ((float*)Cout)[(size_t)(r0+r)*ldc + c] = v;
      }
    }
  }
}

extern "C" void kernel_launch(void* const* d_in, const int* in_sizes, int n_in,
                              void* d_out, int out_size, void* d_ws, size_t ws_size,
                              hipStream_t stream)
{
  const int*   ids    = (const int*)d_in[0];
  const int*   tsteps = (const int*)d_in[1];
  const float* tok    = (const float*)d_in[2];
  const float* tw1    = (const float*)d_in[3];
  const float* tb1    = (const float*)d_in[4];
  const float* tw2    = (const float*)d_in[5];
  const float* tb2    = (const float*)d_in[6];
  const float* n1s    = (const float*)d_in[7];
  const float* n1b    = (const float*)d_in[8];
  // d_in[9] = xW, unused by the reference
  const float* zW     = (const float*)d_in[10];
  const float* pW     = (const float*)d_in[11];
  const float* cW     = (const float*)d_in[12];
  const float* dtW    = (const float*)d_in[13];
  const float* dtb    = (const float*)d_in[14];
  const float* alog   = (const float*)d_in[15];
  const float* Dp     = (const float*)d_in[16];
  const float* oW     = (const float*)d_in[17];
  const float* n2s    = (const float*)d_in[18];
  const float* n2b    = (const float*)d_in[19];
  const float* m1W    = (const float*)d_in[20];
  const float* m1b    = (const float*)d_in[21];
  const float* m2W    = (const float*)d_in[22];
  const float* m2b    = (const float*)d_in[23];
  const float* nos    = (const float*)d_in[24];
  const float* nob    = (const float*)d_in[25];
  const float* hW     = (const float*)d_in[26];
  const float* hb     = (const float*)d_in[27];

  float* ws = (float*)d_ws;
  const size_t MEG = 1u<<20;
  float*  x   = ws;                    // 1M floats
  float*  xn  = ws + 1*MEG;
  float*  z   = ws + 2*MEG;
  float*  dt  = ws + 3*MEG;
  float*  u   = ws + 4*MEG;
  float*  y   = ws + 5*MEG;
  float*  p   = ws + 6*MEG;            // 96K floats
  float*  t0  = ws + 6*MEG + 131072;
  float*  t1  = t0 + 2048;
  float*  t2  = t1 + 8192;
  ushort* xnb = (ushort*)(ws + 6*MEG + 262144);   // 1M ushorts (0.5M floats)
  ushort* y2b = (ushort*)(ws + 6*MEG + 786432);   // 1M ushorts
  ushort* h1b = (ushort*)(ws + 7*MEG + 262144);   // 4M ushorts (2M floats)
  ushort* wb  = (ushort*)(ws + 9*MEG + 262144);   // up to 16.4M ushorts (8.2M floats)
  // total ws usage ~= 17.5M floats = 70 MB

  dim3 blk(256);
  k_temb0<<<dim3(4),  blk, 0, stream>>>(tsteps, t0);
  k_temb1<<<dim3(32), blk, 0, stream>>>(t0, tw1, tb1, t1);
  k_temb2<<<dim3(8),  blk, 0, stream>>>(t1, tw2, tb2, t2);
  k_embed<<<dim3(4096), blk, 0, stream>>>(ids, tok, t2, x);

  for (int l=0; l<4; l++){
    k_ln<<<dim3(1024), blk, 0, stream>>>(x, n1s + l*1024, n1b + l*1024, xn, xnb);
    // z = xn @ zW^T  (bf16 MFMA)
    k_cvt<<<dim3(1024), blk, 0, stream>>>(zW + (size_t)l*1024*1024, wb, 262144);
    k_bgemm<0,false><<<dim3(8,8), blk, 0, stream>>>(xnb, wb, nullptr, nullptr, z, 1024, 1024);
    // p = xn @ pW^T  (fp32, tiny)
    k_gemm<0><<<dim3(1,8),  blk, 0, stream>>>(xn, 1024, pW + (size_t)l*96*1024, nullptr, p, 96, 1024);
    // dt = softplus(p[:,:64] @ dtW^T + dtb)
    k_gemm<3><<<dim3(8,8),  blk, 0, stream>>>(p, 96, dtW + (size_t)l*1024*64, dtb + l*1024, dt, 1024, 64);
    k_conv<<<dim3(4096), blk, 0, stream>>>(xn, cW + l*1024*4, u);
    k_scan<<<dim3(128), blk, 0, stream>>>(dt, u, p, alog + l*1024*16, y);
    k_ypost<<<dim3(4096), blk, 0, stream>>>(y, u, z, Dp + l*1024, y2b);
    // x += y2 @ oW^T
    k_cvt<<<dim3(1024), blk, 0, stream>>>(oW + (size_t)l*1024*1024, wb, 262144);
    k_bgemm<4,false><<<dim3(8,8), blk, 0, stream>>>(y2b, wb, nullptr, x, x, 1024, 1024);
    // MLP
    k_ln<<<dim3(1024), blk, 0, stream>>>(x, n2s + l*1024, n2b + l*1024, xn, xnb);
    k_cvt<<<dim3(4096), blk, 0, stream>>>(m1W + (size_t)l*4096*1024, wb, 1048576);
    k_bgemm<2,true><<<dim3(32,8), blk, 0, stream>>>(xnb, wb, m1b + l*4096, nullptr, h1b, 4096, 1024);
    k_cvt<<<dim3(4096), blk, 0, stream>>>(m2W + (size_t)l*1024*4096, wb, 1048576);
    k_bgemm<5,false><<<dim3(8,8), blk, 0, stream>>>(h1b, wb, m2b + l*1024, x, x, 1024, 4096);
  }
  k_ln<<<dim3(1024), blk, 0, stream>>>(x, nos, nob, xn, xnb);
  // head in two N-halves (keeps wb at 16000*1024 bf16 = 32.8 MB)
  for (int h=0; h<2; h++){
    k_cvt<<<dim3(16000), blk, 0, stream>>>(hW + (size_t)h*16000*1024, wb, 4096000);
    k_bgemm<1,false><<<dim3(125,8), blk, 0, stream>>>(xnb, wb, hb + h*16000, nullptr,
                                                      (float*)d_out + h*16000, 32000, 1024);
  }
}

// Round 3
// 1716.516 us; speedup vs baseline: 4.1198x; 1.6791x over previous
//
#include <hip/hip_runtime.h>
#include <math.h>

// HydraScaleLM forward. Round 3: chunk-parallel fused SSM scan (block per (b,d),
// 16 chunks x 16 n, LDS combine, ypost fused); p-GEMM moved to bf16 MFMA with
// zero-padded weights; bf16 MFMA (m97 structure) for all big GEMMs.
// Shapes: B=2, S=512, D=1024, DEPTH=4, N=16, K=4, R=64, MLP=4096, V=32000. M=1024.

#define DEV __device__ __forceinline__
typedef unsigned int u32;
typedef unsigned short ushort;
typedef __bf16 bf16x8 __attribute__((ext_vector_type(8)));
typedef float f32x4 __attribute__((ext_vector_type(4)));

DEV float silu_f(float x){ return x / (1.f + expf(-x)); }
DEV float gelu_f(float x){ return 0.5f * x * (1.f + erff(x * 0.70710678118654752f)); }
DEV float softplus_f(float x){ return (x > 20.f) ? x : log1pf(expf(x)); }
DEV ushort f2b(float f){
  u32 u = __builtin_bit_cast(u32, f);
  return (ushort)((u + 0x7fffu + ((u >> 16) & 1u)) >> 16);
}

DEV void gl_lds16(const ushort* g, ushort* l){
  __builtin_amdgcn_global_load_lds(
      (const __attribute__((address_space(1))) u32*)g,
      (__attribute__((address_space(3))) u32*)l, 16, 0, 0);
}

// ---------------- fp32 -> bf16 conversion (weights) ----------------
__global__ __launch_bounds__(256) void k_cvt(const float* __restrict__ in, ushort* __restrict__ out, int n4){
  int i = blockIdx.x*256 + threadIdx.x;
  if (i >= n4) return;
  float4 v = ((const float4*)in)[i];
  ushort4 o; o.x=f2b(v.x); o.y=f2b(v.y); o.z=f2b(v.z); o.w=f2b(v.w);
  ((ushort4*)out)[i] = o;
}

// convert [rows_in][1024] fp32 -> [128][1024] bf16, zero rows >= rows_in
__global__ __launch_bounds__(256) void k_cvtpad(const float* __restrict__ in, ushort* __restrict__ out,
                                                int rows_in, int total4){
  int i = blockIdx.x*256 + threadIdx.x;
  if (i >= total4) return;
  int row = (i*4) >> 10;
  ushort4 o;
  if (row < rows_in){
    float4 v = ((const float4*)in)[i];
    o.x=f2b(v.x); o.y=f2b(v.y); o.z=f2b(v.z); o.w=f2b(v.w);
  } else { o.x=0; o.y=0; o.z=0; o.w=0; }
  ((ushort4*)out)[i] = o;
}

// ---------------- time embedding ----------------
__global__ __launch_bounds__(256) void k_temb0(const int* __restrict__ ts, float* __restrict__ temb0){
  int t = blockIdx.x*256 + threadIdx.x;
  if (t >= 2*512) return;
  int b = t >> 9, i = t & 511;
  float tv = (float)ts[b];
  float inv = expf(-(9.210340371976184f/512.f) * (float)i);
  float a = tv * inv;
  temb0[b*1024 + i]       = sinf(a);
  temb0[b*1024 + 512 + i] = cosf(a);
}

__global__ __launch_bounds__(256) void k_temb1(const float* __restrict__ t0, const float* __restrict__ w1,
                                               const float* __restrict__ b1, float* __restrict__ t1){
  int t = blockIdx.x*256 + threadIdx.x;
  int b = t >> 12, j = t & 4095;
  const float4* xr = (const float4*)(t0 + b*1024);
  const float4* wr = (const float4*)(w1 + (size_t)j*1024);
  float acc = 0.f;
  for (int k=0;k<256;k++){ float4 x4=xr[k], w4=wr[k];
    acc += x4.x*w4.x + x4.y*w4.y + x4.z*w4.z + x4.w*w4.w; }
  t1[t] = silu_f(acc + b1[j]);
}

__global__ __launch_bounds__(256) void k_temb2(const float* __restrict__ t1, const float* __restrict__ w2,
                                               const float* __restrict__ b2, float* __restrict__ t2){
  int t = blockIdx.x*256 + threadIdx.x;
  int b = t >> 10, j = t & 1023;
  const float4* xr = (const float4*)(t1 + b*4096);
  const float4* wr = (const float4*)(w2 + (size_t)j*4096);
  float acc = 0.f;
  for (int k=0;k<1024;k++){ float4 x4=xr[k], w4=wr[k];
    acc += x4.x*w4.x + x4.y*w4.y + x4.z*w4.z + x4.w*w4.w; }
  t2[t] = acc + b2[j];
}

// ---------------- embed ----------------
__global__ __launch_bounds__(256) void k_embed(const int* __restrict__ ids, const float* __restrict__ tok,
                                               const float* __restrict__ t2, float* __restrict__ x){
  int i = blockIdx.x*256 + threadIdx.x;
  int bs = i >> 10, d = i & 1023;
  int id = ids[bs];
  x[i] = tok[(size_t)id*1024 + d] + t2[((bs >> 9) << 10) + d];
}

// ---------------- layernorm: writes fp32 + bf16 ----------------
__global__ __launch_bounds__(256) void k_ln(const float* __restrict__ x, const float* __restrict__ sc,
                                            const float* __restrict__ bi, float* __restrict__ o,
                                            ushort* __restrict__ obf){
  int row = blockIdx.x;
  int t = threadIdx.x;
  float4 v = ((const float4*)(x + (size_t)row*1024))[t];
  float sum = v.x+v.y+v.z+v.w;
  float sq  = v.x*v.x+v.y*v.y+v.z*v.z+v.w*v.w;
  for (int o_=32;o_;o_>>=1){ sum += __shfl_down(sum,o_); sq += __shfl_down(sq,o_); }
  __shared__ float ps[8];
  int lane = t & 63, wid = t >> 6;
  if (lane==0){ ps[wid]=sum; ps[4+wid]=sq; }
  __syncthreads();
  float tot = ps[0]+ps[1]+ps[2]+ps[3];
  float tsq = ps[4]+ps[5]+ps[6]+ps[7];
  float m = tot * (1.f/1024.f);
  float var = tsq*(1.f/1024.f) - m*m;
  float r = rsqrtf(var + 1e-5f);
  float4 s4 = ((const float4*)sc)[t];
  float4 b4 = ((const float4*)bi)[t];
  float4 o4;
  o4.x = (v.x-m)*r*s4.x + b4.x;
  o4.y = (v.y-m)*r*s4.y + b4.y;
  o4.z = (v.z-m)*r*s4.z + b4.z;
  o4.w = (v.w-m)*r*s4.w + b4.w;
  ((float4*)(o + (size_t)row*1024))[t] = o4;
  ushort4 ob; ob.x=f2b(o4.x); ob.y=f2b(o4.y); ob.z=f2b(o4.z); ob.w=f2b(o4.w);
  ((ushort4*)(obf + (size_t)row*1024))[t] = ob;
}

// ---------------- causal depthwise conv (K=4) + silu ----------------
__global__ __launch_bounds__(256) void k_conv(const float* __restrict__ xn, const float* __restrict__ cw,
                                              float* __restrict__ u){
  int i = blockIdx.x*256 + threadIdx.x;
  int bs = i >> 10, d = i & 1023;
  int s = bs & 511;
  const float* w = cw + d*4;
  float acc = 0.f;
  #pragma unroll
  for (int j=0;j<4;j++){
    int sj = s - 3 + j;
    if (sj >= 0) acc += xn[i + (j-3)*1024] * w[j];
  }
  u[i] = silu_f(acc);
}

// ---------------- fused chunk-parallel SSM scan + ypost ----------------
// block per (b,d): 256 threads = 16 chunks x 16 n, S=512 -> 32 steps/chunk.
// Phase A: per-chunk (prod At, h_end) from h=0. LDS combine -> per-chunk h0.
// Phase C: rescan with true h0, reduce over n, fused (y+u*Dp)*silu(z) -> bf16.
__global__ __launch_bounds__(256) void k_scanf(
    const float* __restrict__ dt, const float* __restrict__ u,
    const float* __restrict__ p,  const float* __restrict__ alog,
    const float* __restrict__ z,  const float* __restrict__ Dp,
    ushort* __restrict__ y2b)
{
  const int d = blockIdx.x & 1023;
  const int b = blockIdx.x >> 10;
  const int tid = threadIdx.x;
  const int c = tid >> 4, n = tid & 15;
  const float al = alog[d*16 + n];
  const float A = -expf(al);
  const float invA = 1.f/(A + 1e-10f);
  const bool tiny = fabsf(A) < 1e-8f;
  const float dscale = Dp[d];
  const size_t base = (size_t)b*512*1024 + d;
  const float* pp = p + (size_t)b*512*96;
  const int s0 = c*32;

  __shared__ float sA[256], sB[256], sH[256];

  // phase A
  float h = 0.f, pa = 1.f;
  for (int s8=0; s8<32; s8++){
    int s = s0 + s8;
    float dtv = dt[base + (size_t)s*1024];
    float uv  = u [base + (size_t)s*1024];
    float Bpv = pp[s*96 + 64 + n];
    float At = expf(dtv*A);
    float Bt = tiny ? dtv : (At-1.f)*invA;
    h = At*h + Bt*Bpv*uv;
    pa *= At;
  }
  sA[tid]=pa; sB[tid]=h;
  __syncthreads();
  if (tid < 16){
    float H = 0.f;
    #pragma unroll
    for (int c2=0;c2<16;c2++){
      sH[c2*16+tid] = H;
      H = sA[c2*16+tid]*H + sB[c2*16+tid];
    }
  }
  __syncthreads();

  // phase C
  h = sH[tid];
  for (int s8=0; s8<32; s8++){
    int s = s0 + s8;
    float dtv = dt[base + (size_t)s*1024];
    float uv  = u [base + (size_t)s*1024];
    float Bpv = pp[s*96 + 64 + n];
    float Cpv = pp[s*96 + 80 + n];
    float At = expf(dtv*A);
    float Bt = tiny ? dtv : (At-1.f)*invA;
    h = At*h + Bt*Bpv*uv;
    float cc = Cpv*h;
    cc += __shfl_xor(cc,1);
    cc += __shfl_xor(cc,2);
    cc += __shfl_xor(cc,4);
    cc += __shfl_xor(cc,8);
    if (n==0){
      float zv = z[base + (size_t)s*1024];
      y2b[base + (size_t)s*1024] = f2b((cc + uv*dscale) * (zv/(1.f+expf(-zv))));
    }
  }
}

// ---------------- fp32 GEMM (dt only) ----------------
template<int EPI>
__global__ __launch_bounds__(256) void k_gemm(
    const float* __restrict__ A, int lda,
    const float* __restrict__ W,
    const float* __restrict__ bias,
    float* __restrict__ C,
    int N, int K)
{
  __shared__ float As[8][128];
  __shared__ float Bs[8][128];
  const int t = threadIdx.x;
  const int m0 = blockIdx.y * 128;
  const int n0 = blockIdx.x * 128;
  const int tx = t & 15, ty = t >> 4;
  const int srow = t >> 1;
  const int skq  = (t & 1) * 4;
  float acc[8][8];
  #pragma unroll
  for (int i=0;i<8;i++)
    #pragma unroll
    for (int j=0;j<8;j++) acc[i][j]=0.f;

  const float* Aptr = A + (size_t)(m0 + srow)*lda + skq;
  const int gn = n0 + srow;
  const bool bvalid = (gn < N);
  const float* Wptr = W + (size_t)(bvalid ? gn : 0)*K + skq;

  for (int k0 = 0; k0 < K; k0 += 8){
    float4 av = *(const float4*)(Aptr + k0);
    float4 bv = bvalid ? *(const float4*)(Wptr + k0) : make_float4(0.f,0.f,0.f,0.f);
    __syncthreads();
    As[skq+0][srow]=av.x; As[skq+1][srow]=av.y; As[skq+2][srow]=av.z; As[skq+3][srow]=av.w;
    Bs[skq+0][srow]=bv.x; Bs[skq+1][srow]=bv.y; Bs[skq+2][srow]=bv.z; Bs[skq+3][srow]=bv.w;
    __syncthreads();
    #pragma unroll
    for (int k=0;k<8;k++){
      float4 a0 = *(const float4*)&As[k][ty*8];
      float4 a1 = *(const float4*)&As[k][ty*8+4];
      float4 b0 = *(const float4*)&Bs[k][tx*8];
      float4 b1 = *(const float4*)&Bs[k][tx*8+4];
      float ar[8]={a0.x,a0.y,a0.z,a0.w,a1.x,a1.y,a1.z,a1.w};
      float br[8]={b0.x,b0.y,b0.z,b0.w,b1.x,b1.y,b1.z,b1.w};
      #pragma unroll
      for (int i=0;i<8;i++)
        #pragma unroll
        for (int j=0;j<8;j++)
          acc[i][j] = fmaf(ar[i], br[j], acc[i][j]);
    }
  }
  #pragma unroll
  for (int i=0;i<8;i++){
    int m = m0 + ty*8 + i;
    #pragma unroll
    for (int j=0;j<8;j++){
      int n = n0 + tx*8 + j;
      if (n < N){
        float v = acc[i][j];
        if constexpr (EPI==3) v = softplus_f(v + bias[n]);
        C[(size_t)m*N + n] = v;
      }
    }
  }
}

// ---------------- bf16 MFMA GEMM ----------------
// 128x128 tile, BK=64, 4 waves (2x2), 4x4 fragments of 16x16x32 MFMA.
// EPI: 0=none, 1=+bias, 2=+bias,gelu, 4=+resid, 5=+bias,+resid. OBF: bf16 out.
// nmax clamps output columns (p-GEMM writes only 96 of 128).
template<int EPI, bool OBF>
__global__ __launch_bounds__(256) void k_bgemm(
    const ushort* __restrict__ A,
    const ushort* __restrict__ W,
    const float* __restrict__ bias,
    const float* __restrict__ resid,
    void* __restrict__ Cout,
    int ldc, int nmax, int K)
{
  __shared__ ushort As[128*64] __attribute__((aligned(16)));
  __shared__ ushort Bs[128*64] __attribute__((aligned(16)));
  const int t = threadIdx.x;
  const int w = t >> 6;
  const int lane = t & 63;
  const int wm = w >> 1, wn = w & 1;
  const int m0 = blockIdx.y * 128;
  const int n0 = blockIdx.x * 128;

  f32x4 acc[4][4];
  #pragma unroll
  for (int i=0;i<4;i++)
    #pragma unroll
    for (int j=0;j<4;j++) acc[i][j] = (f32x4){0.f,0.f,0.f,0.f};

  const int srow = (lane >> 3);
  const int scol = (lane & 7) * 8;

  for (int k0 = 0; k0 < K; k0 += 64){
    __syncthreads();
    #pragma unroll
    for (int i=0;i<4;i++){
      int chunk = i*4 + w;
      int row = chunk*8 + srow;
      gl_lds16(A + (size_t)(m0 + row)*K + k0 + scol, &As[chunk*512]);
      gl_lds16(W + (size_t)(n0 + row)*K + k0 + scol, &Bs[chunk*512]);
    }
    __syncthreads();
    #pragma unroll
    for (int kk=0; kk<2; ++kk){
      bf16x8 a[4], b[4];
      const int cofs = kk*32 + (lane>>4)*8;
      const int fr = lane & 15;
      #pragma unroll
      for (int am=0; am<4; am++)
        a[am] = *(const bf16x8*)&As[(wm*64 + am*16 + fr)*64 + cofs];
      #pragma unroll
      for (int bn=0; bn<4; bn++)
        b[bn] = *(const bf16x8*)&Bs[(wn*64 + bn*16 + fr)*64 + cofs];
      #pragma unroll
      for (int am=0; am<4; am++)
        #pragma unroll
        for (int bn=0; bn<4; bn++)
          acc[am][bn] = __builtin_amdgcn_mfma_f32_16x16x32_bf16(a[am], b[bn], acc[am][bn], 0, 0, 0);
    }
  }

  #pragma unroll
  for (int am=0; am<4; am++){
    #pragma unroll
    for (int bn=0; bn<4; bn++){
      int r0 = m0 + wm*64 + am*16 + ((lane>>4)<<2);
      int c  = n0 + wn*64 + bn*16 + (lane&15);
      if (c >= nmax) continue;
      float bv = 0.f;
      if constexpr (EPI==1 || EPI==2 || EPI==5) bv = bias[c];
      #pragma unroll
      for (int r=0; r<4; r++){
        float v = acc[am][bn][r];
        if constexpr (EPI==1 || EPI==2 || EPI==5) v += bv;
        if constexpr (EPI==2) v = gelu_f(v);
        if constexpr (EPI==4 || EPI==5) v += resid[(size_t)(r0+r)*ldc + c];
        if constexpr (OBF)
          ((ushort*)Cout)[(size_t)(r0+r)*ldc + c] = f2b(v);
        else
          ((float*)Cout)[(size_t)(r0+r)*ldc + c] = v;
      }
    }
  }
}

extern "C" void kernel_launch(void* const* d_in, const int* in_sizes, int n_in,
                              void* d_out, int out_size, void* d_ws, size_t ws_size,
                              hipStream_t stream)
{
  const int*   ids    = (const int*)d_in[0];
  const int*   tsteps = (const int*)d_in[1];
  const float* tok    = (const float*)d_in[2];
  const float* tw1    = (const float*)d_in[3];
  const float* tb1    = (const float*)d_in[4];
  const float* tw2    = (const float*)d_in[5];
  const float* tb2    = (const float*)d_in[6];
  const float* n1s    = (const float*)d_in[7];
  const float* n1b    = (const float*)d_in[8];
  // d_in[9] = xW, unused by the reference
  const float* zW     = (const float*)d_in[10];
  const float* pW     = (const float*)d_in[11];
  const float* cW     = (const float*)d_in[12];
  const float* dtW    = (const float*)d_in[13];
  const float* dtb    = (const float*)d_in[14];
  const float* alog   = (const float*)d_in[15];
  const float* Dp     = (const float*)d_in[16];
  const float* oW     = (const float*)d_in[17];
  const float* n2s    = (const float*)d_in[18];
  const float* n2b    = (const float*)d_in[19];
  const float* m1W    = (const float*)d_in[20];
  const float* m1b    = (const float*)d_in[21];
  const float* m2W    = (const float*)d_in[22];
  const float* m2b    = (const float*)d_in[23];
  const float* nos    = (const float*)d_in[24];
  const float* nob    = (const float*)d_in[25];
  const float* hW     = (const float*)d_in[26];
  const float* hb     = (const float*)d_in[27];

  float* ws = (float*)d_ws;
  const size_t MEG = 1u<<20;
  float*  x   = ws;                    // 1M floats
  float*  xn  = ws + 1*MEG;
  float*  z   = ws + 2*MEG;
  float*  dt  = ws + 3*MEG;
  float*  u   = ws + 4*MEG;
  float*  p   = ws + 6*MEG;            // 1024x96 fp32
  float*  t0  = ws + 6*MEG + 131072;
  float*  t1  = t0 + 2048;
  float*  t2  = t1 + 8192;
  ushort* wbp = (ushort*)(ws + 6*MEG + 143360);   // padded pW: 128x1024 bf16
  ushort* xnb = (ushort*)(ws + 6*MEG + 262144);   // 1M ushorts
  ushort* y2b = (ushort*)(ws + 6*MEG + 786432);   // 1M ushorts
  ushort* h1b = (ushort*)(ws + 7*MEG + 262144);   // 4M ushorts
  ushort* wb  = (ushort*)(ws + 9*MEG + 262144);   // up to 16.4M ushorts

  dim3 blk(256);
  k_temb0<<<dim3(4),  blk, 0, stream>>>(tsteps, t0);
  k_temb1<<<dim3(32), blk, 0, stream>>>(t0, tw1, tb1, t1);
  k_temb2<<<dim3(8),  blk, 0, stream>>>(t1, tw2, tb2, t2);
  k_embed<<<dim3(4096), blk, 0, stream>>>(ids, tok, t2, x);

  for (int l=0; l<4; l++){
    k_ln<<<dim3(1024), blk, 0, stream>>>(x, n1s + l*1024, n1b + l*1024, xn, xnb);
    // z = xn @ zW^T
    k_cvt<<<dim3(1024), blk, 0, stream>>>(zW + (size_t)l*1024*1024, wb, 262144);
    k_bgemm<0,false><<<dim3(8,8), blk, 0, stream>>>(xnb, wb, nullptr, nullptr, z, 1024, 1024, 1024);
    // p = xn @ pW^T  (bf16 MFMA, padded to 128 rows, fp32 out, 96 cols)
    k_cvtpad<<<dim3(128), blk, 0, stream>>>(pW + (size_t)l*96*1024, wbp, 96, 32768);
    k_bgemm<0,false><<<dim3(1,8), blk, 0, stream>>>(xnb, wbp, nullptr, nullptr, p, 96, 96, 1024);
    // dt = softplus(p[:,:64] @ dtW^T + dtb)  (fp32)
    k_gemm<3><<<dim3(8,8),  blk, 0, stream>>>(p, 96, dtW + (size_t)l*1024*64, dtb + l*1024, dt, 1024, 64);
    k_conv<<<dim3(4096), blk, 0, stream>>>(xn, cW + l*1024*4, u);
    // fused scan + (y + u*Dp)*silu(z) -> y2b (bf16)
    k_scanf<<<dim3(2048), blk, 0, stream>>>(dt, u, p, alog + l*1024*16, z, Dp + l*1024, y2b);
    // x += y2 @ oW^T
    k_cvt<<<dim3(1024), blk, 0, stream>>>(oW + (size_t)l*1024*1024, wb, 262144);
    k_bgemm<4,false><<<dim3(8,8), blk, 0, stream>>>(y2b, wb, nullptr, x, x, 1024, 1024, 1024);
    // MLP
    k_ln<<<dim3(1024), blk, 0, stream>>>(x, n2s + l*1024, n2b + l*1024, xn, xnb);
    k_cvt<<<dim3(4096), blk, 0, stream>>>(m1W + (size_t)l*4096*1024, wb, 1048576);
    k_bgemm<2,true><<<dim3(32,8), blk, 0, stream>>>(xnb, wb, m1b + l*4096, nullptr, h1b, 4096, 4096, 1024);
    k_cvt<<<dim3(4096), blk, 0, stream>>>(m2W + (size_t)l*1024*4096, wb, 1048576);
    k_bgemm<5,false><<<dim3(8,8), blk, 0, stream>>>(h1b, wb, m2b + l*1024, x, x, 1024, 1024, 4096);
  }
  k_ln<<<dim3(1024), blk, 0, stream>>>(x, nos, nob, xn, xnb);
  // head in two N-halves
  for (int h=0; h<2; h++){
    k_cvt<<<dim3(16000), blk, 0, stream>>>(hW + (size_t)h*16000*1024, wb, 4096000);
    k_bgemm<1,false><<<dim3(125,8), blk, 0, stream>>>(xnb, wb, hb + h*16000, nullptr,
                                                      (float*)d_out + h*16000, 32000, 32000, 1024);
  }
}